// Round 5
// baseline (431.462 us; speedup 1.0000x reference)
//
#include <hip/hip_runtime.h>

#define FD 128  // feature dim, fixed by problem

typedef __attribute__((ext_vector_type(8))) short short8;   // 8 bf16 in 4 VGPRs
typedef __attribute__((ext_vector_type(4))) float floatx4;  // MFMA acc

__device__ inline unsigned short f2bf(float f) {  // fp32 -> bf16 bits, RNE
  unsigned u = __float_as_uint(f);
  u += 0x7fffu + ((u >> 16) & 1u);
  return (unsigned short)(u >> 16);
}
__device__ inline float bf2f(unsigned short s) {
  return __uint_as_float(((unsigned)s) << 16);
}
__device__ inline float lo16f(unsigned v) { return __uint_as_float(v << 16); }
__device__ inline float hi16f(unsigned v) { return __uint_as_float(v & 0xffff0000u); }
__device__ inline int imin(int a, int b) { return a < b ? a : b; }

// ---------------- CSR construction ----------------

// per-256-block exclusive scan + block totals + dis = rsqrt(deg+1)
__global__ __launch_bounds__(256) void k_scanA(const int* __restrict__ deg,
                                               int* __restrict__ offtmp,
                                               int* __restrict__ bsum,
                                               float* __restrict__ dis, int N) {
  __shared__ int s[256];
  int i = blockIdx.x * 256 + threadIdx.x;
  int v = (i < N) ? deg[i] : 0;
  if (i < N) dis[i] = rsqrtf((float)(v + 1));  // +1 self-loop
  s[threadIdx.x] = v;
  __syncthreads();
#pragma unroll
  for (int ofs = 1; ofs < 256; ofs <<= 1) {
    int t = (threadIdx.x >= ofs) ? s[threadIdx.x - ofs] : 0;
    __syncthreads();
    s[threadIdx.x] += t;
    __syncthreads();
  }
  if (i < N) offtmp[i] = s[threadIdx.x] - v;  // exclusive
  if (threadIdx.x == 255) bsum[blockIdx.x] = s[255];
}

// parallel exclusive scan of block sums (nb <= 512)
__global__ __launch_bounds__(512) void k_scanB(int* __restrict__ bsum, int nb) {
  __shared__ int s[512];
  int t = threadIdx.x;
  int v = (t < nb) ? bsum[t] : 0;
  s[t] = v;
  __syncthreads();
#pragma unroll
  for (int ofs = 1; ofs < 512; ofs <<= 1) {
    int u = (t >= ofs) ? s[t - ofs] : 0;
    __syncthreads();
    s[t] += u;
    __syncthreads();
  }
  if (t < nb) bsum[t] = s[t] - v;  // exclusive
}

__global__ __launch_bounds__(256) void k_scanC(const int* __restrict__ offtmp,
                                               const int* __restrict__ bsum,
                                               int* __restrict__ off, int N, int E) {
  int i = blockIdx.x * 256 + threadIdx.x;
  if (i < N) off[i] = offtmp[i] + bsum[i >> 8];
  if (i == 0) off[N] = E;
}

// packed edge record: .x = src, .y = bits(dis[src]*dis[dst])
__global__ __launch_bounds__(256) void k_fill(const int* __restrict__ src,
                                              const int* __restrict__ dst,
                                              const float* __restrict__ dis,
                                              const int* __restrict__ off,
                                              int* __restrict__ cursor,
                                              int2* __restrict__ ew, int E) {
  int e = blockIdx.x * 256 + threadIdx.x;
  if (e >= E) return;
  int d = dst[e], s = src[e];
  int pos = off[d] + atomicAdd(&cursor[d], 1);
  ew[pos] = make_int2(s, __float_as_int(dis[s] * dis[d]));
}

// ---------------- W pre-swizzle: fp32 W -> hi/lo bf16 in MFMA B-frag order ----
// Wf[ct][kt][lane][j]: k = kt*32 + (lane>>4)*8 + j, n = ct*16 + (lane&15)
__global__ __launch_bounds__(256) void k_wsplit(const float* __restrict__ W,
                                                short* __restrict__ hi,
                                                short* __restrict__ lo) {
  int idx = blockIdx.x * 256 + threadIdx.x;  // 0..16383
  int j = idx & 7, lane = (idx >> 3) & 63, kt = (idx >> 9) & 3, ct = idx >> 11;
  int k = kt * 32 + (lane >> 4) * 8 + j;
  int n = ct * 16 + (lane & 15);
  float w = W[k * FD + n];
  unsigned short h = f2bf(w);
  hi[idx] = (short)h;
  lo[idx] = (short)f2bf(w - bf2f(h));
}

// ---------------- GEMM body: H(bf16) = A @ W via bf16 MFMA ----------------
// W hi (and optionally lo) fragments staged in LDS. 4 waves/block, 32 rows/wave.
// ABF16=false: A fp32, split hi/lo in-register. WLO: apply W low-order correction.
template <bool ABF16, bool WLO>
__device__ __forceinline__ void gemm_body(const void* __restrict__ Av,
                                          const short* __restrict__ Wf_hi,
                                          const short* __restrict__ Wf_lo,
                                          unsigned short* __restrict__ H, int N,
                                          int blk, short* whi, short* wlo) {
  int tid = threadIdx.x;
#pragma unroll
  for (int it = 0; it < 8; ++it) {
    int idx = (it * 256 + tid) * 8;  // 16 B per thread per iter
    *(short8*)&whi[idx] = *(const short8*)&Wf_hi[idx];
    if (WLO) *(short8*)&wlo[idx] = *(const short8*)&Wf_lo[idx];
  }
  __syncthreads();

  int wid = tid >> 6, lane = tid & 63;
  int quad = lane >> 4, m = lane & 15;
  int rbase = blk * 128 + wid * 32;

  short8 ahi[2][4], alo[2][4];
#pragma unroll
  for (int t = 0; t < 2; ++t) {
    int arow = rbase + t * 16 + m;
    if (arow >= N) arow = N - 1;  // clamp; OOB rows never stored
    if (ABF16) {
      const unsigned short* ap = (const unsigned short*)Av + (size_t)arow * FD;
#pragma unroll
      for (int kt = 0; kt < 4; ++kt)
        ahi[t][kt] = *(const short8*)(ap + kt * 32 + quad * 8);
    } else {
      const float* ap = (const float*)Av + (size_t)arow * FD;
#pragma unroll
      for (int kt = 0; kt < 4; ++kt) {
        const float* p = ap + kt * 32 + quad * 8;
        float4 a0 = *(const float4*)p;
        float4 a1 = *(const float4*)(p + 4);
        float av[8] = {a0.x, a0.y, a0.z, a0.w, a1.x, a1.y, a1.z, a1.w};
#pragma unroll
        for (int j = 0; j < 8; ++j) {
          unsigned short hb = f2bf(av[j]);
          ahi[t][kt][j] = (short)hb;
          alo[t][kt][j] = (short)f2bf(av[j] - bf2f(hb));
        }
      }
    }
  }

#pragma unroll
  for (int ct = 0; ct < 8; ++ct) {
    floatx4 acc0 = {0.f, 0.f, 0.f, 0.f}, acc1 = {0.f, 0.f, 0.f, 0.f};
#pragma unroll
    for (int kt = 0; kt < 4; ++kt) {
      int fo = (((ct << 2) + kt) * 64 + lane) * 8;
      short8 bhi = *(const short8*)&whi[fo];
      acc0 = __builtin_amdgcn_mfma_f32_16x16x32_bf16(ahi[0][kt], bhi, acc0, 0, 0, 0);
      acc1 = __builtin_amdgcn_mfma_f32_16x16x32_bf16(ahi[1][kt], bhi, acc1, 0, 0, 0);
      if (!ABF16) {
        acc0 = __builtin_amdgcn_mfma_f32_16x16x32_bf16(alo[0][kt], bhi, acc0, 0, 0, 0);
        acc1 = __builtin_amdgcn_mfma_f32_16x16x32_bf16(alo[1][kt], bhi, acc1, 0, 0, 0);
      }
      if (WLO) {
        short8 blo = *(const short8*)&wlo[fo];
        acc0 = __builtin_amdgcn_mfma_f32_16x16x32_bf16(ahi[0][kt], blo, acc0, 0, 0, 0);
        acc1 = __builtin_amdgcn_mfma_f32_16x16x32_bf16(ahi[1][kt], blo, acc1, 0, 0, 0);
      }
    }
    // C/D: row = quad*4 + reg, col = lane&15
#pragma unroll
    for (int r = 0; r < 4; ++r) {
      int row0 = rbase + quad * 4 + r;
      int row1 = rbase + 16 + quad * 4 + r;
      if (row0 < N) H[(size_t)row0 * FD + ct * 16 + m] = f2bf(acc0[r]);
      if (row1 < N) H[(size_t)row1 * FD + ct * 16 + m] = f2bf(acc1[r]);
    }
  }
}

// bf16-A GEMM (layers 1,2): 32 KB LDS
__global__ __launch_bounds__(256) void k_gemm_b(const unsigned short* __restrict__ A,
                                                const short* __restrict__ Wf_hi,
                                                unsigned short* __restrict__ H, int N) {
  __shared__ short whi[FD * FD];
  gemm_body<true, false>(A, Wf_hi, nullptr, H, N, blockIdx.x, whi, nullptr);
}

// fused layer-0 GEMM (fp32 A, W hi+lo) + edge histogram (independent work)
__global__ __launch_bounds__(256) void k_gemm0_count(const float* __restrict__ A,
                                                     const short* __restrict__ Wf_hi,
                                                     const short* __restrict__ Wf_lo,
                                                     unsigned short* __restrict__ H, int N,
                                                     int gemmBlocks,
                                                     const int* __restrict__ dst,
                                                     int* __restrict__ deg, int E) {
  __shared__ short whi[FD * FD];
  __shared__ short wlo[FD * FD];
  if ((int)blockIdx.x < gemmBlocks) {
    gemm_body<false, true>(A, Wf_hi, Wf_lo, H, N, blockIdx.x, whi, wlo);
  } else {
    int e = ((int)blockIdx.x - gemmBlocks) * 256 + threadIdx.x;
    if (e < E) atomicAdd(&deg[dst[e]], 1);
  }
}

// ---------------- Aggregation: out = relu(A_norm @ h + b), h is bf16 --------
// One wave per node (100k waves). 8-edge groups, fully predicated (no tail),
// next group's ew prefetched during gathers; 4 independent accumulator pairs.
template <bool OUTBF16>
__global__ __launch_bounds__(256) void k_agg(const unsigned int* __restrict__ h,
                                             const int* __restrict__ off,
                                             const int2* __restrict__ ew,
                                             const float* __restrict__ dis,
                                             const float* __restrict__ bias,
                                             void* __restrict__ out, int N) {
  int lane = threadIdx.x & 63;
  int i = blockIdx.x * 4 + (threadIdx.x >> 6);
  if (i >= N) return;
  int p0 = off[i], p1 = off[i + 1];
  float di = dis[i];
  float ws = di * di;
  unsigned v = h[(size_t)i * 64 + lane];
  float a0 = ws * lo16f(v), a1 = ws * hi16f(v);
  float b0 = 0.f, b1 = 0.f, c0 = 0.f, c1 = 0.f, d0 = 0.f, d1 = 0.f;

  if (p0 < p1) {
    int pe1 = p1 - 1;
    int2 eb[8];
#pragma unroll
    for (int j = 0; j < 8; ++j) eb[j] = ew[imin(p0 + j, pe1)];
    for (int p = p0; p < p1; p += 8) {
      unsigned g[8];
#pragma unroll
      for (int j = 0; j < 8; ++j) g[j] = h[(size_t)eb[j].x * 64 + lane];
      int2 enx[8];
#pragma unroll
      for (int j = 0; j < 8; ++j) enx[j] = ew[imin(p + 8 + j, pe1)];
#pragma unroll
      for (int j = 0; j < 8; ++j) {
        float w = (p + j < p1) ? __int_as_float(eb[j].y) : 0.f;
        float l = lo16f(g[j]), hh = hi16f(g[j]);
        if (j == 0 || j == 4) { a0 = fmaf(w, l, a0); a1 = fmaf(w, hh, a1); }
        else if (j == 1 || j == 5) { b0 = fmaf(w, l, b0); b1 = fmaf(w, hh, b1); }
        else if (j == 2 || j == 6) { c0 = fmaf(w, l, c0); c1 = fmaf(w, hh, c1); }
        else { d0 = fmaf(w, l, d0); d1 = fmaf(w, hh, d1); }
      }
#pragma unroll
      for (int j = 0; j < 8; ++j) eb[j] = enx[j];
    }
  }

  float2 bb = ((const float2*)bias)[lane];
  float o0 = fmaxf((a0 + b0) + (c0 + d0) + bb.x, 0.f);
  float o1 = fmaxf((a1 + b1) + (c1 + d1) + bb.y, 0.f);
  if (OUTBF16) {
    unsigned pk = ((unsigned)f2bf(o1) << 16) | (unsigned)f2bf(o0);
    ((unsigned*)out)[(size_t)i * 64 + lane] = pk;
  } else {
    ((float2*)out)[(size_t)i * 64 + lane] = make_float2(o0, o1);
  }
}

// ---------------- launch ----------------

extern "C" void kernel_launch(void* const* d_in, const int* in_sizes, int n_in,
                              void* d_out, int out_size, void* d_ws, size_t ws_size,
                              hipStream_t stream) {
  const float* x = (const float*)d_in[0];
  const int* ei = (const int*)d_in[1];
  const float* Wg = (const float*)d_in[2];
  const float* b = (const float*)d_in[3];
  int N = in_sizes[0] / FD;
  int E = in_sizes[1] / 2;
  const int* src = ei;      // edge_index[0]
  const int* dst = ei + E;  // edge_index[1]

  char* p = (char*)d_ws;
  auto alloc = [&](size_t bytes) {
    void* r = (void*)p;
    p += (bytes + 255) & ~(size_t)255;
    return r;
  };
  int* deg = (int*)alloc((size_t)N * 8);  // deg[N] then cursor[N], one memset
  int* cursor = deg + N;
  float* dis = (float*)alloc((size_t)N * 4);
  int* offtmp = (int*)alloc((size_t)N * 4);
  int nb = (N + 255) / 256;
  int* bsum = (int*)alloc((size_t)nb * 4);
  int* off = (int*)alloc((size_t)(N + 1) * 4);
  int2* ew = (int2*)alloc((size_t)E * 8);
  unsigned short* h = (unsigned short*)alloc((size_t)N * FD * 2);   // bf16 H
  unsigned short* xb = (unsigned short*)alloc((size_t)N * FD * 2);  // bf16 x (layers 1,2)
  short* wf_hi = (short*)alloc((size_t)FD * FD * 2);
  short* wf_lo = (short*)alloc((size_t)FD * FD * 2);

  hipMemsetAsync(deg, 0, (size_t)N * 8, stream);

  int gE = (E + 255) / 256, gN = (N + 255) / 256;
  int gG = (N + 127) / 128;
  int gA = (N + 3) / 4;

  k_wsplit<<<FD * FD / 256, 256, 0, stream>>>(Wg, wf_hi, wf_lo);
  // layer-0 GEMM fused with the independent edge histogram
  k_gemm0_count<<<gG + gE, 256, 0, stream>>>(x, wf_hi, wf_lo, h, N, gG, dst, deg, E);
  k_scanA<<<nb, 256, 0, stream>>>(deg, offtmp, bsum, dis, N);
  k_scanB<<<1, 512, 0, stream>>>(bsum, nb);
  k_scanC<<<gN, 256, 0, stream>>>(offtmp, bsum, off, N, E);
  k_fill<<<gE, 256, 0, stream>>>(src, dst, dis, off, cursor, ew, E);

  // layer 0 aggregate -> bf16 xb
  k_agg<true><<<gA, 256, 0, stream>>>((const unsigned*)h, off, ew, dis, b, xb, N);
  // layer 1: bf16 xb -> h (W hi only); agg -> bf16 xb
  k_gemm_b<<<gG, 256, 0, stream>>>(xb, wf_hi, h, N);
  k_agg<true><<<gA, 256, 0, stream>>>((const unsigned*)h, off, ew, dis, b, xb, N);
  // layer 2: bf16 xb -> h (W hi only); agg -> fp32 d_out
  k_gemm_b<<<gG, 256, 0, stream>>>(xb, wf_hi, h, N);
  k_agg<false><<<gA, 256, 0, stream>>>((const unsigned*)h, off, ew, dis, b, d_out, N);
}

// Round 6
// 335.862 us; speedup vs baseline: 1.2846x; 1.2846x over previous
//
#include <hip/hip_runtime.h>

#define FD 128  // feature dim, fixed by problem

typedef __attribute__((ext_vector_type(8))) short short8;   // 8 bf16 in 4 VGPRs
typedef __attribute__((ext_vector_type(4))) float floatx4;  // MFMA acc

__device__ inline unsigned short f2bf(float f) {  // fp32 -> bf16 bits, RNE
  unsigned u = __float_as_uint(f);
  u += 0x7fffu + ((u >> 16) & 1u);
  return (unsigned short)(u >> 16);
}
__device__ inline float bf2f(unsigned short s) {
  return __uint_as_float(((unsigned)s) << 16);
}
__device__ inline float lo16f(unsigned v) { return __uint_as_float(v << 16); }
__device__ inline float hi16f(unsigned v) { return __uint_as_float(v & 0xffff0000u); }
__device__ inline int imin(int a, int b) { return a < b ? a : b; }

// ---------------- fused: zero deg/cursor + W pre-swizzle ----------------
// blocks [0, zBlocks): zero 2N ints. blocks [zBlocks, zBlocks+64): split W into
// hi/lo bf16 in MFMA B-frag order: idx -> k = kt*32+(lane>>4)*8+j, n = ct*16+(lane&15)
__global__ __launch_bounds__(256) void k_wsplit_zero(const float* __restrict__ W,
                                                     short* __restrict__ hi,
                                                     short* __restrict__ lo,
                                                     int* __restrict__ zbuf, int zn,
                                                     int zBlocks) {
  int b = blockIdx.x;
  if (b < zBlocks) {
    int i = b * 256 + threadIdx.x;
    if (i < zn) zbuf[i] = 0;
  } else {
    int idx = (b - zBlocks) * 256 + threadIdx.x;  // 0..16383
    int j = idx & 7, lane = (idx >> 3) & 63, kt = (idx >> 9) & 3, ct = idx >> 11;
    int k = kt * 32 + (lane >> 4) * 8 + j;
    int n = ct * 16 + (lane & 15);
    float w = W[k * FD + n];
    unsigned short h = f2bf(w);
    hi[idx] = (short)h;
    lo[idx] = (short)f2bf(w - bf2f(h));
  }
}

// ---------------- CSR construction ----------------

// per-256-block exclusive scan + block totals + dis = rsqrt(deg+1)
__global__ __launch_bounds__(256) void k_scanA(const int* __restrict__ deg,
                                               int* __restrict__ offtmp,
                                               int* __restrict__ bsum,
                                               float* __restrict__ dis, int N) {
  __shared__ int s[256];
  int i = blockIdx.x * 256 + threadIdx.x;
  int v = (i < N) ? deg[i] : 0;
  if (i < N) dis[i] = rsqrtf((float)(v + 1));  // +1 self-loop
  s[threadIdx.x] = v;
  __syncthreads();
#pragma unroll
  for (int ofs = 1; ofs < 256; ofs <<= 1) {
    int t = (threadIdx.x >= ofs) ? s[threadIdx.x - ofs] : 0;
    __syncthreads();
    s[threadIdx.x] += t;
    __syncthreads();
  }
  if (i < N) offtmp[i] = s[threadIdx.x] - v;  // exclusive
  if (threadIdx.x == 255) bsum[blockIdx.x] = s[255];
}

// parallel exclusive scan of block sums (nb <= 512)
__global__ __launch_bounds__(512) void k_scanB(int* __restrict__ bsum, int nb) {
  __shared__ int s[512];
  int t = threadIdx.x;
  int v = (t < nb) ? bsum[t] : 0;
  s[t] = v;
  __syncthreads();
#pragma unroll
  for (int ofs = 1; ofs < 512; ofs <<= 1) {
    int u = (t >= ofs) ? s[t - ofs] : 0;
    __syncthreads();
    s[t] += u;
    __syncthreads();
  }
  if (t < nb) bsum[t] = s[t] - v;  // exclusive
}

// fused: blocks [0,cBlocks) write off[] (for k_agg); blocks [cBlocks,...) fill
// CSR edge records, computing the node base inline (off[] not needed yet).
// packed edge record: .x = src, .y = bits(dis[src]*dis[dst])
__global__ __launch_bounds__(256) void k_fill_scanC(const int* __restrict__ src,
                                                    const int* __restrict__ dst,
                                                    const float* __restrict__ dis,
                                                    const int* __restrict__ offtmp,
                                                    const int* __restrict__ bsum,
                                                    int* __restrict__ off,
                                                    int* __restrict__ cursor,
                                                    int2* __restrict__ ew,
                                                    int N, int E, int cBlocks) {
  int b = blockIdx.x;
  if (b < cBlocks) {
    int i = b * 256 + threadIdx.x;
    if (i < N) off[i] = offtmp[i] + bsum[i >> 8];
    if (i == 0) off[N] = E;
  } else {
    int e = (b - cBlocks) * 256 + threadIdx.x;
    if (e < E) {
      int d = dst[e], s = src[e];
      int base = offtmp[d] + bsum[d >> 8];
      int pos = base + atomicAdd(&cursor[d], 1);
      ew[pos] = make_int2(s, __float_as_int(dis[s] * dis[d]));
    }
  }
}

// ---------------- GEMM body: H(bf16) = A @ W via bf16 MFMA ----------------
// W hi (and optionally lo) fragments staged in LDS. 4 waves/block, 32 rows/wave.
// ABF16=false: A fp32, split hi/lo in-register. WLO: apply W low-order correction.
template <bool ABF16, bool WLO>
__device__ __forceinline__ void gemm_body(const void* __restrict__ Av,
                                          const short* __restrict__ Wf_hi,
                                          const short* __restrict__ Wf_lo,
                                          unsigned short* __restrict__ H, int N,
                                          int blk, short* whi, short* wlo) {
  int tid = threadIdx.x;
#pragma unroll
  for (int it = 0; it < 8; ++it) {
    int idx = (it * 256 + tid) * 8;  // 16 B per thread per iter
    *(short8*)&whi[idx] = *(const short8*)&Wf_hi[idx];
    if (WLO) *(short8*)&wlo[idx] = *(const short8*)&Wf_lo[idx];
  }
  __syncthreads();

  int wid = tid >> 6, lane = tid & 63;
  int quad = lane >> 4, m = lane & 15;
  int rbase = blk * 128 + wid * 32;

  short8 ahi[2][4], alo[2][4];
#pragma unroll
  for (int t = 0; t < 2; ++t) {
    int arow = rbase + t * 16 + m;
    if (arow >= N) arow = N - 1;  // clamp; OOB rows never stored
    if (ABF16) {
      const unsigned short* ap = (const unsigned short*)Av + (size_t)arow * FD;
#pragma unroll
      for (int kt = 0; kt < 4; ++kt)
        ahi[t][kt] = *(const short8*)(ap + kt * 32 + quad * 8);
    } else {
      const float* ap = (const float*)Av + (size_t)arow * FD;
#pragma unroll
      for (int kt = 0; kt < 4; ++kt) {
        const float* p = ap + kt * 32 + quad * 8;
        float4 a0 = *(const float4*)p;
        float4 a1 = *(const float4*)(p + 4);
        float av[8] = {a0.x, a0.y, a0.z, a0.w, a1.x, a1.y, a1.z, a1.w};
#pragma unroll
        for (int j = 0; j < 8; ++j) {
          unsigned short hb = f2bf(av[j]);
          ahi[t][kt][j] = (short)hb;
          alo[t][kt][j] = (short)f2bf(av[j] - bf2f(hb));
        }
      }
    }
  }

#pragma unroll
  for (int ct = 0; ct < 8; ++ct) {
    floatx4 acc0 = {0.f, 0.f, 0.f, 0.f}, acc1 = {0.f, 0.f, 0.f, 0.f};
#pragma unroll
    for (int kt = 0; kt < 4; ++kt) {
      int fo = (((ct << 2) + kt) * 64 + lane) * 8;
      short8 bhi = *(const short8*)&whi[fo];
      acc0 = __builtin_amdgcn_mfma_f32_16x16x32_bf16(ahi[0][kt], bhi, acc0, 0, 0, 0);
      acc1 = __builtin_amdgcn_mfma_f32_16x16x32_bf16(ahi[1][kt], bhi, acc1, 0, 0, 0);
      if (!ABF16) {
        acc0 = __builtin_amdgcn_mfma_f32_16x16x32_bf16(alo[0][kt], bhi, acc0, 0, 0, 0);
        acc1 = __builtin_amdgcn_mfma_f32_16x16x32_bf16(alo[1][kt], bhi, acc1, 0, 0, 0);
      }
      if (WLO) {
        short8 blo = *(const short8*)&wlo[fo];
        acc0 = __builtin_amdgcn_mfma_f32_16x16x32_bf16(ahi[0][kt], blo, acc0, 0, 0, 0);
        acc1 = __builtin_amdgcn_mfma_f32_16x16x32_bf16(ahi[1][kt], blo, acc1, 0, 0, 0);
      }
    }
    // C/D: row = quad*4 + reg, col = lane&15
#pragma unroll
    for (int r = 0; r < 4; ++r) {
      int row0 = rbase + quad * 4 + r;
      int row1 = rbase + 16 + quad * 4 + r;
      if (row0 < N) H[(size_t)row0 * FD + ct * 16 + m] = f2bf(acc0[r]);
      if (row1 < N) H[(size_t)row1 * FD + ct * 16 + m] = f2bf(acc1[r]);
    }
  }
}

// bf16-A GEMM (layers 1,2): 32 KB LDS
__global__ __launch_bounds__(256) void k_gemm_b(const unsigned short* __restrict__ A,
                                                const short* __restrict__ Wf_hi,
                                                unsigned short* __restrict__ H, int N) {
  __shared__ short whi[FD * FD];
  gemm_body<true, false>(A, Wf_hi, nullptr, H, N, blockIdx.x, whi, nullptr);
}

// fused layer-0 GEMM (fp32 A, W hi+lo) + edge histogram (independent work)
__global__ __launch_bounds__(256) void k_gemm0_count(const float* __restrict__ A,
                                                     const short* __restrict__ Wf_hi,
                                                     const short* __restrict__ Wf_lo,
                                                     unsigned short* __restrict__ H, int N,
                                                     int gemmBlocks,
                                                     const int* __restrict__ dst,
                                                     int* __restrict__ deg, int E) {
  __shared__ short whi[FD * FD];
  __shared__ short wlo[FD * FD];
  if ((int)blockIdx.x < gemmBlocks) {
    gemm_body<false, true>(A, Wf_hi, Wf_lo, H, N, blockIdx.x, whi, wlo);
  } else {
    int e = ((int)blockIdx.x - gemmBlocks) * 256 + threadIdx.x;
    if (e < E) atomicAdd(&deg[dst[e]], 1);
  }
}

// ---------------- Aggregation: out = relu(A_norm @ h + b), h is bf16 --------
// One wave per node; lane holds 1 dword = 2 bf16 features. Node's edge list is
// split into two halves walked as two independent chains, 2 edges per chain per
// iteration -> 4 independent ew->gather miss chains, <=3 wasted slots per node.
template <bool OUTBF16>
__global__ __launch_bounds__(256) void k_agg(const unsigned int* __restrict__ h,
                                             const int* __restrict__ off,
                                             const int2* __restrict__ ew,
                                             const float* __restrict__ dis,
                                             const float* __restrict__ bias,
                                             void* __restrict__ out, int N) {
  int wid = __builtin_amdgcn_readfirstlane(threadIdx.x >> 6);  // wave-uniform
  int lane = threadIdx.x & 63;
  int i = blockIdx.x * 4 + wid;
  if (i >= N) return;
  int p0 = off[i], p1 = off[i + 1];
  float di = dis[i];
  float wsf = di * di;
  unsigned v = h[(size_t)i * 64 + lane];
  float a0 = wsf * lo16f(v), a1 = wsf * hi16f(v);
  float b0 = 0.f, b1 = 0.f, c0 = 0.f, c1 = 0.f, d0 = 0.f, d1 = 0.f;

  if (p0 < p1) {
    int lenA = (p1 - p0 + 1) >> 1;  // chain A: [p0, p0+lenA)
    int qb = p0 + lenA;             // chain B: [qb, p1)
    int lastA = qb - 1, lastB = p1 - 1;
    for (int s = 0; s < lenA; s += 2) {
      int iA0 = p0 + s;
      int iA1 = imin(iA0 + 1, lastA);
      int iB0 = imin(qb + s, lastB);
      int iB1 = imin(qb + s + 1, lastB);
      int2 eA0 = ew[iA0], eA1 = ew[iA1], eB0 = ew[iB0], eB1 = ew[iB1];
      unsigned gA0 = h[(size_t)eA0.x * 64 + lane];
      unsigned gA1 = h[(size_t)eA1.x * 64 + lane];
      unsigned gB0 = h[(size_t)eB0.x * 64 + lane];
      unsigned gB1 = h[(size_t)eB1.x * 64 + lane];
      float wA0 = __int_as_float(eA0.y);
      float wA1 = (s + 1 < lenA) ? __int_as_float(eA1.y) : 0.f;
      float wB0 = (qb + s < p1) ? __int_as_float(eB0.y) : 0.f;
      float wB1 = (qb + s + 1 < p1) ? __int_as_float(eB1.y) : 0.f;
      a0 = fmaf(wA0, lo16f(gA0), a0); a1 = fmaf(wA0, hi16f(gA0), a1);
      b0 = fmaf(wA1, lo16f(gA1), b0); b1 = fmaf(wA1, hi16f(gA1), b1);
      c0 = fmaf(wB0, lo16f(gB0), c0); c1 = fmaf(wB0, hi16f(gB0), c1);
      d0 = fmaf(wB1, lo16f(gB1), d0); d1 = fmaf(wB1, hi16f(gB1), d1);
    }
  }

  float2 bb = ((const float2*)bias)[lane];
  float o0 = fmaxf((a0 + b0) + (c0 + d0) + bb.x, 0.f);
  float o1 = fmaxf((a1 + b1) + (c1 + d1) + bb.y, 0.f);
  if (OUTBF16) {
    unsigned pk = ((unsigned)f2bf(o1) << 16) | (unsigned)f2bf(o0);
    ((unsigned*)out)[(size_t)i * 64 + lane] = pk;
  } else {
    ((float2*)out)[(size_t)i * 64 + lane] = make_float2(o0, o1);
  }
}

// ---------------- launch ----------------

extern "C" void kernel_launch(void* const* d_in, const int* in_sizes, int n_in,
                              void* d_out, int out_size, void* d_ws, size_t ws_size,
                              hipStream_t stream) {
  const float* x = (const float*)d_in[0];
  const int* ei = (const int*)d_in[1];
  const float* Wg = (const float*)d_in[2];
  const float* b = (const float*)d_in[3];
  int N = in_sizes[0] / FD;
  int E = in_sizes[1] / 2;
  const int* src = ei;      // edge_index[0]
  const int* dst = ei + E;  // edge_index[1]

  char* p = (char*)d_ws;
  auto alloc = [&](size_t bytes) {
    void* r = (void*)p;
    p += (bytes + 255) & ~(size_t)255;
    return r;
  };
  int* deg = (int*)alloc((size_t)N * 8);  // deg[N] then cursor[N], zeroed together
  int* cursor = deg + N;
  float* dis = (float*)alloc((size_t)N * 4);
  int* offtmp = (int*)alloc((size_t)N * 4);
  int nb = (N + 255) / 256;
  int* bsum = (int*)alloc((size_t)nb * 4);
  int* off = (int*)alloc((size_t)(N + 1) * 4);
  int2* ew = (int2*)alloc((size_t)E * 8);
  unsigned short* h = (unsigned short*)alloc((size_t)N * FD * 2);   // bf16 H
  unsigned short* xb = (unsigned short*)alloc((size_t)N * FD * 2);  // bf16 x (layers 1,2)
  short* wf_hi = (short*)alloc((size_t)FD * FD * 2);
  short* wf_lo = (short*)alloc((size_t)FD * FD * 2);

  int gE = (E + 255) / 256, gN = (N + 255) / 256;
  int gG = (N + 127) / 128;
  int gA = (N + 3) / 4;
  int zn = 2 * N;
  int zB = (zn + 255) / 256;

  // zero deg+cursor, swizzle/split W (independent block ranges)
  k_wsplit_zero<<<zB + FD * FD / 256, 256, 0, stream>>>(Wg, wf_hi, wf_lo, deg, zn, zB);
  // layer-0 GEMM fused with the independent edge histogram
  k_gemm0_count<<<gG + gE, 256, 0, stream>>>(x, wf_hi, wf_lo, h, N, gG, dst, deg, E);
  k_scanA<<<nb, 256, 0, stream>>>(deg, offtmp, bsum, dis, N);
  k_scanB<<<1, 512, 0, stream>>>(bsum, nb);
  // off[] write fused with CSR fill (fill computes node base inline)
  k_fill_scanC<<<gN + gE, 256, 0, stream>>>(src, dst, dis, offtmp, bsum, off, cursor,
                                            ew, N, E, gN);

  // layer 0 aggregate -> bf16 xb
  k_agg<true><<<gA, 256, 0, stream>>>((const unsigned*)h, off, ew, dis, b, xb, N);
  // layer 1: bf16 xb -> h (W hi only); agg -> bf16 xb
  k_gemm_b<<<gG, 256, 0, stream>>>(xb, wf_hi, h, N);
  k_agg<true><<<gA, 256, 0, stream>>>((const unsigned*)h, off, ew, dis, b, xb, N);
  // layer 2: bf16 xb -> h (W hi only); agg -> fp32 d_out
  k_gemm_b<<<gG, 256, 0, stream>>>(xb, wf_hi, h, N);
  k_agg<false><<<gA, 256, 0, stream>>>((const unsigned*)h, off, ew, dis, b, d_out, N);
}